// Round 11
// baseline (66.617 us; speedup 1.0000x reference)
//
#include <hip/hip_runtime.h>
#include <hip/hip_bf16.h>

typedef __attribute__((ext_vector_type(8))) short bf16x8;
typedef __attribute__((ext_vector_type(4))) float f32x4;

#define NPIX 4096
#define NC   128
#define RS128 0.08838834764831845f   // 1/sqrt(128)

// ---------------- prep (fused scan + copy + pack), 1024 thr — unchanged ----------------
__global__ __launch_bounds__(1024) void sffa_prep(
    const float* __restrict__ x, const float* __restrict__ mask,
    ushort* __restrict__ KnW, ushort* __restrict__ QW, ushort* __restrict__ VtW,
    float* __restrict__ s0c, int* __restrict__ pixQ, int* __restrict__ cnts,
    float* __restrict__ out)
{
    __shared__ float xs[128][69];
    __shared__ float ms[64];
    __shared__ float rinv[64];
    __shared__ float ssum[64];
    __shared__ float2 part[16][64];
    __shared__ int se[64];
    __shared__ int bgn[64];
    __shared__ int tinfo[2];
    __shared__ int wredP[16], wredT[16];
    const int tid = threadIdx.x;
    const int b = blockIdx.x >> 6, nblk = blockIdx.x & 63;
    const int n0 = nblk * 64;
    const float* xb = x + (size_t)b * NC * NPIX;
    float* ob = out + (size_t)b * NC * NPIX;

    #pragma unroll
    for (int it = 0; it < 2; ++it) {
        int e4 = it * 1024 + tid;
        int c = e4 >> 4, n4 = (e4 & 15) * 4;
        float4 v = *(const float4*)(xb + (size_t)c * NPIX + n0 + n4);
        xs[c][n4+0] = v.x; xs[c][n4+1] = v.y; xs[c][n4+2] = v.z; xs[c][n4+3] = v.w;
        *(float4*)(ob + (size_t)c * NPIX + n0 + n4) = v;
    }
    if (tid < 16) {
        float4 mv = *(const float4*)(mask + (size_t)b * NPIX + n0 + tid * 4);
        ms[tid*4+0] = mv.x; ms[tid*4+1] = mv.y; ms[tid*4+2] = mv.z; ms[tid*4+3] = mv.w;
    }
    {
        const int lane = tid & 63, w = tid >> 6;
        float4 mv = *(const float4*)(mask + (size_t)b * NPIX + tid * 4);
        int f0 = mv.x < 0.5f ? 0x10000 : 1;
        int f1 = mv.y < 0.5f ? 0x10000 : 1;
        int f2 = mv.z < 0.5f ? 0x10000 : 1;
        int f3 = mv.w < 0.5f ? 0x10000 : 1;
        int p0 = tid * 4;
        int pre = 0, tot = f0 + f1 + f2 + f3;
        if (p0 + 0 < n0) pre += f0;
        if (p0 + 1 < n0) pre += f1;
        if (p0 + 2 < n0) pre += f2;
        if (p0 + 3 < n0) pre += f3;
        #pragma unroll
        for (int d = 1; d < 64; d <<= 1) {
            pre += __shfl_xor(pre, d);
            tot += __shfl_xor(tot, d);
        }
        if (lane == 0) { wredP[w] = pre; wredT[w] = tot; }
    }
    __syncthreads();
    if (tid < 64) {
        int vP = (tid < 16) ? wredP[tid] : 0;
        int vT = (tid < 16) ? wredT[tid] : 0;
        #pragma unroll
        for (int d = 1; d < 16; d <<= 1) {
            vP += __shfl_xor(vP, d);
            vT += __shfl_xor(vT, d);
        }
        int base  = __shfl(vP, 0);
        int total = __shfl(vT, 0);
        if (tid == 0 && nblk == 0) {
            cnts[b * 2]     = total & 0xffff;
            cnts[b * 2 + 1] = total >> 16;
        }
        int f = ms[tid] > 0.5f ? 1 : 0x10000;
        int s = f;
        #pragma unroll
        for (int d = 1; d < 64; d <<= 1) {
            int t = __shfl_up(s, d);
            if (tid >= d) s += t;
        }
        se[tid] = base + s - f;
    }
    __syncthreads();
    {
        int p = tid & 63, qd = tid >> 6;
        float m = ms[p];
        float s2 = 0.f, s1 = 0.f;
        #pragma unroll
        for (int i = 0; i < 8; ++i) {
            float xv = xs[qd*8 + i][p];
            float k = fmaf(xv, m, 1e-7f);
            s2 = fmaf(k, k, s2);
            s1 += xv;
        }
        part[qd][p] = make_float2(s2, s1);
    }
    __syncthreads();
    if (tid < 64) {
        float s2 = 0.f, s1 = 0.f;
        #pragma unroll
        for (int k = 0; k < 16; ++k) { float2 t = part[k][tid]; s2 += t.x; s1 += t.y; }
        rinv[tid] = rsqrtf(s2);
        ssum[tid] = s1 * RS128;
    }
    __syncthreads();
    #pragma unroll
    for (int it = 0; it < 4; ++it) {
        int e2 = it * 1024 + tid;
        int n = e2 >> 6, cp = (e2 & 63) * 2;
        int pe = se[n];
        float x0 = xs[cp][n], x1 = xs[cp+1][n];
        if (ms[n] > 0.5f) {
            int slot = pe & 0xffff;
            float k0 = x0 + 1e-7f, k1 = x1 + 1e-7f;
            float r = rinv[n];
            __hip_bfloat162 kn;
            kn.x = __float2bfloat16(k0 * r); kn.y = __float2bfloat16(k1 * r);
            *(__hip_bfloat162*)(KnW + ((size_t)b * NPIX + slot) * NC + cp) = kn;
        } else {
            int slot = pe >> 16;
            __hip_bfloat162 q;
            q.x = __float2bfloat16(x0); q.y = __float2bfloat16(x1);
            *(__hip_bfloat162*)(QW + ((size_t)b * NPIX + slot) * NC + cp) = q;
        }
    }
    if (tid < 64) {
        if (ms[tid] < 0.5f) {
            int slot = se[tid] >> 16;
            s0c [(size_t)b * NPIX + slot] = ssum[tid];
            pixQ[(size_t)b * NPIX + slot] = n0 + tid;
        } else {
            bgn[(se[tid] & 0xffff) - (se[0] & 0xffff)] = tid;
        }
    }
    if (tid == 0) {
        tinfo[0] = se[0] & 0xffff;
        tinfo[1] = (se[63] & 0xffff) + (ms[63] > 0.5f ? 1 : 0) - (se[0] & 0xffff);
    }
    __syncthreads();
    {
        const int s0b = tinfo[0], nbg = tinfo[1];
        const int j = tid & 63, cg = tid >> 6;
        if (j < nbg) {
            int n = bgn[j];
            ushort* vcol = VtW + (size_t)b * NC * NPIX + s0b + j;
            #pragma unroll
            for (int cc = 0; cc < 8; ++cc) {
                int c = cg * 8 + cc;
                __hip_bfloat16 h = __float2bfloat16(xs[c][n] + 1e-7f);
                vcol[(size_t)c * NPIX] = *(ushort*)&h;
            }
        }
    }
}

// ---------------- flash attention: 32-query blocks, 128-key tiles, fused scatter ----
// Geometry: 8 waves = 2 q-strips(16q) x 4 key-quarters(32k). 256 active blocks.
#define L_BUFSZ 65536     // {K 32KB, V 32KB} per buffer, double-buffered
#define L_P   131072      // 8 waves * 1280
#define L_ML  141312      // ma[4][32], la[4][32]
#define L_SCL 142336
#define L_PIX 142464
#define L_SZ  142592

__global__ __launch_bounds__(512, 2) void sffa_attn(
    const ushort* __restrict__ KnW, const ushort* __restrict__ QW,
    const ushort* __restrict__ VtW, const int* __restrict__ cnts,
    const float* __restrict__ s0c, const int* __restrict__ pixQ,
    float* __restrict__ out)
{
    __shared__ __align__(16) char smem[L_SZ];
    const int tid  = threadIdx.x;
    const int w = tid >> 6, lane = tid & 63;
    const int l15 = lane & 15, g = lane >> 4;
    const int bx = (int)blockIdx.x;
    const int b = bx >> 7, qblk = bx & 127;
    const int q0 = qblk * 32;
    const int cntK = cnts[b * 2], cntQ = cnts[b * 2 + 1];
    if (q0 >= cntQ) return;

    const int NTK = (cntK + 127) >> 7;
    float* ob = out + (size_t)b * NC * NPIX;

    if (NTK <= 0) {
        if (tid < 32) {
            int slot = q0 + tid;
            if (slot < cntQ) {
                int pix = pixQ[(size_t)b * NPIX + slot];
                for (int c = 0; c < NC; ++c) ob[(size_t)c * NPIX + pix] = 0.f;
            }
        }
        return;
    }

    const int wq = w & 1;     // query strip (16 q)
    const int kq = w >> 1;    // key quarter (32 k of the 128-key tile)

    const ushort* Knb = KnW + (size_t)b * NPIX * NC;
    const ushort* Qb  = QW  + (size_t)b * NPIX * NC + (size_t)q0 * NC;
    const ushort* Vtb = VtW + (size_t)b * NC * NPIX;

    // ---- stage Q tile (8 KB), read q-fragments ----
    {
        int row = tid >> 4, col = (tid & 15) * 16;
        int4 v = ((const int4*)Qb)[tid];
        *(int4*)(smem + row * 256 + (col ^ ((row & 15) << 4))) = v;
    }
    __syncthreads();
    bf16x8 qf[4];
    {
        int qrow = wq * 16 + l15;
        #pragma unroll
        for (int kc = 0; kc < 4; ++kc)
            qf[kc] = *(const bf16x8*)(smem + qrow * 256 + ((64*kc + 16*g) ^ (l15 << 4)));
    }
    __syncthreads();

    // staging address precompute (shared formula for K and V sub-layouts)
    const int sOff = (tid >> 4) * 256 + (((tid & 15) * 16) ^ (((tid >> 4) & 15) << 4));
    const int4* kgbase = (const int4*)Knb;
    const ushort* vg = Vtb + (size_t)(tid >> 4) * NPIX + (tid & 15) * 8;

    int4 prK0, prK1, prK2, prK3, prV0, prV1, prV2, prV3;
    // tile 0 -> buf0
    prK0 = kgbase[tid];        prK1 = kgbase[512 + tid];
    prK2 = kgbase[1024 + tid]; prK3 = kgbase[1536 + tid];
    prV0 = *(const int4*)(vg);
    prV1 = *(const int4*)(vg + (size_t)32 * NPIX);
    prV2 = *(const int4*)(vg + (size_t)64 * NPIX);
    prV3 = *(const int4*)(vg + (size_t)96 * NPIX);
    {
        char* bk = smem, * bv = smem + 32768;
        *(int4*)(bk + sOff)         = prK0;
        *(int4*)(bk + sOff + 8192)  = prK1;
        *(int4*)(bk + sOff + 16384) = prK2;
        *(int4*)(bk + sOff + 24576) = prK3;
        *(int4*)(bv + sOff)         = prV0;
        *(int4*)(bv + sOff + 8192)  = prV1;
        *(int4*)(bv + sOff + 16384) = prV2;
        *(int4*)(bv + sOff + 24576) = prV3;
    }
    if (NTK > 1) {
        prK0 = kgbase[2048 + tid];  prK1 = kgbase[2560 + tid];
        prK2 = kgbase[3072 + tid];  prK3 = kgbase[3584 + tid];
        prV0 = *(const int4*)(vg + 128);
        prV1 = *(const int4*)(vg + (size_t)32 * NPIX + 128);
        prV2 = *(const int4*)(vg + (size_t)64 * NPIX + 128);
        prV3 = *(const int4*)(vg + (size_t)96 * NPIX + 128);
    }
    __syncthreads();

    f32x4 acc[8];
    const f32x4 fzero = {0.f, 0.f, 0.f, 0.f};
    #pragma unroll
    for (int i = 0; i < 8; ++i) acc[i] = fzero;
    float mrun = -1e30f, lrun = 0.f;
    char* Pw = smem + L_P + w * 1280;

    for (int kt = 0; kt < NTK; ++kt) {
        if (kt + 1 < NTK) {
            char* bk = smem + ((kt + 1) & 1) * L_BUFSZ;
            char* bv = bk + 32768;
            *(int4*)(bk + sOff)         = prK0;
            *(int4*)(bk + sOff + 8192)  = prK1;
            *(int4*)(bk + sOff + 16384) = prK2;
            *(int4*)(bk + sOff + 24576) = prK3;
            *(int4*)(bv + sOff)         = prV0;
            *(int4*)(bv + sOff + 8192)  = prV1;
            *(int4*)(bv + sOff + 16384) = prV2;
            *(int4*)(bv + sOff + 24576) = prV3;
        }
        if (kt + 2 < NTK) {
            int kb4 = (kt + 2) * 2048;
            prK0 = kgbase[kb4 + tid];        prK1 = kgbase[kb4 + 512 + tid];
            prK2 = kgbase[kb4 + 1024 + tid]; prK3 = kgbase[kb4 + 1536 + tid];
            const ushort* vgk = vg + (kt + 2) * 128;
            prV0 = *(const int4*)(vgk);
            prV1 = *(const int4*)(vgk + (size_t)32 * NPIX);
            prV2 = *(const int4*)(vgk + (size_t)64 * NPIX);
            prV3 = *(const int4*)(vgk + (size_t)96 * NPIX);
        }
        char* bk = smem + (kt & 1) * L_BUFSZ;
        char* bv = bk + 32768;
        f32x4 sa0 = fzero, sa1 = fzero;
        {
            const char* rb0 = bk + (kq * 32 + l15) * 256;
            const char* rb1 = rb0 + 4096;
            const int sw = l15 << 4;
            __builtin_amdgcn_s_setprio(1);
            #pragma unroll
            for (int kc = 0; kc < 4; ++kc) {
                int off = (64 * kc + 16 * g) ^ sw;
                bf16x8 a0 = *(const bf16x8*)(rb0 + off);
                bf16x8 a1 = *(const bf16x8*)(rb1 + off);
                sa0 = __builtin_amdgcn_mfma_f32_16x16x32_bf16(a0, qf[kc], sa0, 0, 0, 0);
                sa1 = __builtin_amdgcn_mfma_f32_16x16x32_bf16(a1, qf[kc], sa1, 0, 0, 0);
            }
            __builtin_amdgcn_s_setprio(0);
        }
        {
            int kg0 = kt * 128;
            if (kg0 + 128 > cntK) {
                int kb = cntK - kg0;
                int kr = kq * 32 + 4 * g;
                #pragma unroll
                for (int r = 0; r < 4; ++r) {
                    if (kr + r >= kb)      sa0[r] = -3e38f;
                    if (kr + 16 + r >= kb) sa1[r] = -3e38f;
                }
            }
        }
        float tmax = fmaxf(fmaxf(fmaxf(sa0[0], sa0[1]), fmaxf(sa0[2], sa0[3])),
                           fmaxf(fmaxf(sa1[0], sa1[1]), fmaxf(sa1[2], sa1[3])));
        tmax = fmaxf(tmax, __shfl_xor(tmax, 16));
        tmax = fmaxf(tmax, __shfl_xor(tmax, 32));
        bool grow = !__all(tmax <= mrun + 8.f);
        float mnew = grow ? fmaxf(mrun, tmax) : mrun;
        float p0[4], p1[4];
        float ts = 0.f;
        #pragma unroll
        for (int r = 0; r < 4; ++r) { p0[r] = __expf(sa0[r] - mnew); ts += p0[r]; }
        #pragma unroll
        for (int r = 0; r < 4; ++r) { p1[r] = __expf(sa1[r] - mnew); ts += p1[r]; }
        ts += __shfl_xor(ts, 16);
        ts += __shfl_xor(ts, 32);
        if (grow) {
            float sc = __expf(mrun - mnew);
            lrun = lrun * sc + ts;
            float scr[4];
            #pragma unroll
            for (int r = 0; r < 4; ++r) scr[r] = __shfl(sc, 4 * g + r);
            #pragma unroll
            for (int ct = 0; ct < 8; ++ct) {
                acc[ct][0] *= scr[0]; acc[ct][1] *= scr[1];
                acc[ct][2] *= scr[2]; acc[ct][3] *= scr[3];
            }
            mrun = mnew;
        } else {
            lrun += ts;
        }
        union { __hip_bfloat162 h; unsigned u; } ua0, ua1, ub0, ub1;
        ua0.h.x = __float2bfloat16(p0[0]); ua0.h.y = __float2bfloat16(p0[1]);
        ua1.h.x = __float2bfloat16(p0[2]); ua1.h.y = __float2bfloat16(p0[3]);
        ub0.h.x = __float2bfloat16(p1[0]); ub0.h.y = __float2bfloat16(p1[1]);
        ub1.h.x = __float2bfloat16(p1[2]); ub1.h.y = __float2bfloat16(p1[3]);
        *(int2*)(Pw + l15 * 80 +      8 * g) = make_int2((int)ua0.u, (int)ua1.u);
        *(int2*)(Pw + l15 * 80 + 32 + 8 * g) = make_int2((int)ub0.u, (int)ub1.u);
        bf16x8 pf = *(const bf16x8*)(Pw + l15 * 80 + 16 * g);
        {
            __builtin_amdgcn_s_setprio(1);
            #pragma unroll
            for (int ct = 0; ct < 8; ++ct) {
                int c = 16 * ct + l15;
                bf16x8 vf = *(const bf16x8*)(bv + c * 256 +
                                             ((64 * kq + 16 * g) ^ ((c & 15) << 4)));
                acc[ct] = __builtin_amdgcn_mfma_f32_16x16x32_bf16(pf, vf, acc[ct], 0, 0, 0);
            }
            __builtin_amdgcn_s_setprio(0);
        }
        __syncthreads();
    }

    // ---- 4-way key-quarter merge into LDS agg ----
    float* ma = (float*)(smem + L_ML);   // [4][32]
    float* la = ma + 128;
    const int qs = wq * 16 + l15;        // 0..31
    if (g == 0) { ma[kq * 32 + qs] = mrun; la[kq * 32 + qs] = lrun; }
    __syncthreads();
    float* agg = (float*)smem;           // [128][36] fp32, reuses tile buffers
    {
        float mstar = fmaxf(fmaxf(ma[qs], ma[32 + qs]), fmaxf(ma[64 + qs], ma[96 + qs]));
        float f = __expf(mrun - mstar);
        float fr[4];
        #pragma unroll
        for (int r = 0; r < 4; ++r) fr[r] = __shfl(f, 4 * g + r);
        #pragma unroll
        for (int p = 0; p < 4; ++p) {
            if (kq == p) {
                #pragma unroll
                for (int ct = 0; ct < 8; ++ct) {
                    int c = 16 * ct + l15;
                    #pragma unroll
                    for (int r = 0; r < 4; ++r) {
                        int idx = c * 36 + wq * 16 + 4 * g + r;
                        float v = acc[ct][r] * fr[r];
                        if (p == 0) agg[idx] = v;
                        else        agg[idx] += v;
                    }
                }
            }
            __syncthreads();
        }
    }

    // ---- final normalize (fold analytic hole-row) + scatter ----
    float* scl  = (float*)(smem + L_SCL);
    int*   pixS = (int*)(smem + L_PIX);
    const float m0f = (float)(NPIX - cntK);
    if (tid < 32) {
        int slot = q0 + tid;
        int pix = -1;
        float sv = 0.f;
        if (slot < cntQ) {
            pix = pixQ[(size_t)b * NPIX + slot];
            float M = fmaxf(fmaxf(ma[tid], ma[32 + tid]),
                            fmaxf(ma[64 + tid], ma[96 + tid]));
            float ls = la[tid]      * __expf(ma[tid]      - M)
                     + la[32 + tid] * __expf(ma[32 + tid] - M)
                     + la[64 + tid] * __expf(ma[64 + tid] - M)
                     + la[96 + tid] * __expf(ma[96 + tid] - M);
            float s0 = s0c[(size_t)b * NPIX + slot];
            float M2 = fmaxf(M, s0);
            float eM = __expf(M - M2);
            float L  = m0f * __expf(s0 - M2) + ls * eM;
            sv = eM / L;
        }
        scl[tid]  = sv;
        pixS[tid] = pix;
    }
    __syncthreads();
    {
        int c = tid >> 2, j0 = (tid & 3) * 8;
        #pragma unroll
        for (int j = 0; j < 8; ++j) {
            int q = j0 + j;
            int pix = pixS[q];
            if (pix >= 0)
                ob[(size_t)c * NPIX + pix] = agg[c * 36 + q] * scl[q];
        }
    }
}

extern "C" void kernel_launch(void* const* d_in, const int* in_sizes, int n_in,
                              void* d_out, int out_size, void* d_ws, size_t ws_size,
                              hipStream_t stream) {
    const float* x    = (const float*)d_in[0];
    const float* mask = (const float*)d_in[1];
    char* ws = (char*)d_ws;
    const size_t MBy = 1024 * 1024;
    const size_t KBy = 1024;

    ushort* KnW = (ushort*)(ws);                      // 4 MB compact Kn
    ushort* QW  = (ushort*)(ws + 4 * MBy);            // 4 MB compact Q
    ushort* VtW = (ushort*)(ws + 8 * MBy);            // 4 MB compact V^T
    char* tail = ws + 12 * MBy;
    float* s0c  = (float*)(tail);                     // 64 KB
    int*   pixQ = (int*)(tail + 64 * KBy);            // 64 KB
    int*   cnts = (int*)(tail + 128 * KBy);           // 32 B

    sffa_prep <<<256, 1024, 0, stream>>>(x, mask, KnW, QW, VtW, s0c, pixQ, cnts,
                                         (float*)d_out);
    sffa_attn <<<4 * 128, 512, 0, stream>>>(KnW, QW, VtW, cnts, s0c, pixQ,
                                            (float*)d_out);
}

// Round 13
// 62.230 us; speedup vs baseline: 1.0705x; 1.0705x over previous
//
#include <hip/hip_runtime.h>
#include <hip/hip_bf16.h>

typedef __attribute__((ext_vector_type(8))) short bf16x8;
typedef __attribute__((ext_vector_type(4))) float f32x4;

#define NPIX 4096
#define NC   128
#define RS128 0.08838834764831845f   // 1/sqrt(128)

// ---------------- prep (fused scan + copy + pack), 1024 thr — proven ----------------
__global__ __launch_bounds__(1024) void sffa_prep(
    const float* __restrict__ x, const float* __restrict__ mask,
    ushort* __restrict__ KnW, ushort* __restrict__ QW, ushort* __restrict__ VtW,
    float* __restrict__ s0c, int* __restrict__ pixQ, int* __restrict__ cnts,
    float* __restrict__ out)
{
    __shared__ float xs[128][69];
    __shared__ float ms[64];
    __shared__ float rinv[64];
    __shared__ float ssum[64];
    __shared__ float2 part[16][64];
    __shared__ int se[64];
    __shared__ int bgn[64];
    __shared__ int tinfo[2];
    __shared__ int wredP[16], wredT[16];
    const int tid = threadIdx.x;
    const int b = blockIdx.x >> 6, nblk = blockIdx.x & 63;
    const int n0 = nblk * 64;
    const float* xb = x + (size_t)b * NC * NPIX;
    float* ob = out + (size_t)b * NC * NPIX;

    #pragma unroll
    for (int it = 0; it < 2; ++it) {
        int e4 = it * 1024 + tid;
        int c = e4 >> 4, n4 = (e4 & 15) * 4;
        float4 v = *(const float4*)(xb + (size_t)c * NPIX + n0 + n4);
        xs[c][n4+0] = v.x; xs[c][n4+1] = v.y; xs[c][n4+2] = v.z; xs[c][n4+3] = v.w;
        *(float4*)(ob + (size_t)c * NPIX + n0 + n4) = v;
    }
    if (tid < 16) {
        float4 mv = *(const float4*)(mask + (size_t)b * NPIX + n0 + tid * 4);
        ms[tid*4+0] = mv.x; ms[tid*4+1] = mv.y; ms[tid*4+2] = mv.z; ms[tid*4+3] = mv.w;
    }
    {
        const int lane = tid & 63, w = tid >> 6;
        float4 mv = *(const float4*)(mask + (size_t)b * NPIX + tid * 4);
        int f0 = mv.x < 0.5f ? 0x10000 : 1;
        int f1 = mv.y < 0.5f ? 0x10000 : 1;
        int f2 = mv.z < 0.5f ? 0x10000 : 1;
        int f3 = mv.w < 0.5f ? 0x10000 : 1;
        int p0 = tid * 4;
        int pre = 0, tot = f0 + f1 + f2 + f3;
        if (p0 + 0 < n0) pre += f0;
        if (p0 + 1 < n0) pre += f1;
        if (p0 + 2 < n0) pre += f2;
        if (p0 + 3 < n0) pre += f3;
        #pragma unroll
        for (int d = 1; d < 64; d <<= 1) {
            pre += __shfl_xor(pre, d);
            tot += __shfl_xor(tot, d);
        }
        if (lane == 0) { wredP[w] = pre; wredT[w] = tot; }
    }
    __syncthreads();
    if (tid < 64) {
        int vP = (tid < 16) ? wredP[tid] : 0;
        int vT = (tid < 16) ? wredT[tid] : 0;
        #pragma unroll
        for (int d = 1; d < 16; d <<= 1) {
            vP += __shfl_xor(vP, d);
            vT += __shfl_xor(vT, d);
        }
        int base  = __shfl(vP, 0);
        int total = __shfl(vT, 0);
        if (tid == 0 && nblk == 0) {
            cnts[b * 2]     = total & 0xffff;
            cnts[b * 2 + 1] = total >> 16;
        }
        int f = ms[tid] > 0.5f ? 1 : 0x10000;
        int s = f;
        #pragma unroll
        for (int d = 1; d < 64; d <<= 1) {
            int t = __shfl_up(s, d);
            if (tid >= d) s += t;
        }
        se[tid] = base + s - f;
    }
    __syncthreads();
    {
        int p = tid & 63, qd = tid >> 6;
        float m = ms[p];
        float s2 = 0.f, s1 = 0.f;
        #pragma unroll
        for (int i = 0; i < 8; ++i) {
            float xv = xs[qd*8 + i][p];
            float k = fmaf(xv, m, 1e-7f);
            s2 = fmaf(k, k, s2);
            s1 += xv;
        }
        part[qd][p] = make_float2(s2, s1);
    }
    __syncthreads();
    if (tid < 64) {
        float s2 = 0.f, s1 = 0.f;
        #pragma unroll
        for (int k = 0; k < 16; ++k) { float2 t = part[k][tid]; s2 += t.x; s1 += t.y; }
        rinv[tid] = rsqrtf(s2);
        ssum[tid] = s1 * RS128;
    }
    __syncthreads();
    #pragma unroll
    for (int it = 0; it < 4; ++it) {
        int e2 = it * 1024 + tid;
        int n = e2 >> 6, cp = (e2 & 63) * 2;
        int pe = se[n];
        float x0 = xs[cp][n], x1 = xs[cp+1][n];
        if (ms[n] > 0.5f) {
            int slot = pe & 0xffff;
            float k0 = x0 + 1e-7f, k1 = x1 + 1e-7f;
            float r = rinv[n];
            __hip_bfloat162 kn;
            kn.x = __float2bfloat16(k0 * r); kn.y = __float2bfloat16(k1 * r);
            *(__hip_bfloat162*)(KnW + ((size_t)b * NPIX + slot) * NC + cp) = kn;
        } else {
            int slot = pe >> 16;
            __hip_bfloat162 q;
            q.x = __float2bfloat16(x0); q.y = __float2bfloat16(x1);
            *(__hip_bfloat162*)(QW + ((size_t)b * NPIX + slot) * NC + cp) = q;
        }
    }
    if (tid < 64) {
        if (ms[tid] < 0.5f) {
            int slot = se[tid] >> 16;
            s0c [(size_t)b * NPIX + slot] = ssum[tid];
            pixQ[(size_t)b * NPIX + slot] = n0 + tid;
        } else {
            bgn[(se[tid] & 0xffff) - (se[0] & 0xffff)] = tid;
        }
    }
    if (tid == 0) {
        tinfo[0] = se[0] & 0xffff;
        tinfo[1] = (se[63] & 0xffff) + (ms[63] > 0.5f ? 1 : 0) - (se[0] & 0xffff);
    }
    __syncthreads();
    {
        const int s0b = tinfo[0], nbg = tinfo[1];
        const int j = tid & 63, cg = tid >> 6;
        if (j < nbg) {
            int n = bgn[j];
            ushort* vcol = VtW + (size_t)b * NC * NPIX + s0b + j;
            #pragma unroll
            for (int cc = 0; cc < 8; ++cc) {
                int c = cg * 8 + cc;
                __hip_bfloat16 h = __float2bfloat16(xs[c][n] + 1e-7f);
                vcol[(size_t)c * NPIX] = *(ushort*)&h;
            }
        }
    }
}

// ---------------- attn: 4 waves, 32-q blocks (128 qblks!), 64-k tiles, KS split ----
#define L_V   16384
#define L_P   32768      // 4 waves * 1280
#define L_ML  37888      // ma[2][32], la[2][32]
#define L_SZ  38400

__global__ __launch_bounds__(256, 4) void sffa_attn(
    const ushort* __restrict__ KnW, const ushort* __restrict__ QW,
    const ushort* __restrict__ VtW, const int* __restrict__ cnts,
    ushort* __restrict__ partW, float* __restrict__ mlW, int KS)
{
    __shared__ __align__(16) char smem[L_SZ];
    const int tid  = threadIdx.x;
    const int w = tid >> 6, lane = tid & 63;
    const int l15 = lane & 15, g = lane >> 4;
    const int bx = (int)blockIdx.x;
    const int per = 128 * KS;                    // r12 BUG FIX: 128 qblks cover 4096 queries
    const int b = bx / per;
    const int rem = bx - b * per;
    const int qblk = rem / KS, ks = rem - (rem / KS) * KS;
    const int q0 = qblk * 32;
    const int cntK = cnts[b * 2], cntQ = cnts[b * 2 + 1];
    if (q0 >= cntQ) return;
    const int blk = (b * 128 + qblk) * KS + ks;

    const int nk64 = (cntK + 63) >> 6;
    const int tpk  = (nk64 + KS - 1) / KS;
    const int t0   = ks * tpk;
    const int NTK  = min(t0 + tpk, nk64) - t0;

    if (NTK <= 0) {
        int4 z = {0,0,0,0};
        int4* pz = (int4*)(partW + (size_t)blk * 4096);
        pz[tid] = z; pz[256 + tid] = z;
        if (tid < 32)
            *(float2*)(mlW + ((size_t)blk * 32 + tid) * 2) = make_float2(-1e30f, 0.f);
        return;
    }

    const int wq = w & 1;    // query strip (16 q)
    const int kh = w >> 1;   // key half (32 k)
    const int kbase = t0 * 64;

    const ushort* Knb = KnW + (size_t)b * NPIX * NC;
    const ushort* Vtb = VtW + (size_t)b * NC * NPIX;

    // Q fragments straight from global (L2-hot, once per block)
    bf16x8 qf[4];
    {
        const ushort* Qrow = QW + ((size_t)b * NPIX + q0 + wq * 16 + l15) * NC;
        #pragma unroll
        for (int kc = 0; kc < 4; ++kc)
            qf[kc] = *(const bf16x8*)(Qrow + 32 * kc + 8 * g);
    }

    // staging addresses (4 slots each of K and V, 16 KB apiece)
    const int kOff = (tid >> 4) * 256 + (((tid & 15) * 16) ^ (((tid >> 4) & 15) << 4));
    const int vOff = (tid >> 3) * 128 + (((tid & 7) * 16) ^ (((tid >> 3) & 7) << 4));
    const int4* kg = (const int4*)(Knb + (size_t)kbase * NC);
    const ushort* vg = Vtb + (size_t)(tid >> 3) * NPIX + kbase + (tid & 7) * 8;

    int4 prK0, prK1, prK2, prK3, prV0, prV1, prV2, prV3;
    prK0 = kg[tid]; prK1 = kg[256+tid]; prK2 = kg[512+tid]; prK3 = kg[768+tid];
    prV0 = *(const int4*)(vg);
    prV1 = *(const int4*)(vg + (size_t)32 * NPIX);
    prV2 = *(const int4*)(vg + (size_t)64 * NPIX);
    prV3 = *(const int4*)(vg + (size_t)96 * NPIX);
    *(int4*)(smem + kOff)          = prK0;
    *(int4*)(smem + kOff + 4096)   = prK1;
    *(int4*)(smem + kOff + 8192)   = prK2;
    *(int4*)(smem + kOff + 12288)  = prK3;
    *(int4*)(smem + L_V + vOff)         = prV0;
    *(int4*)(smem + L_V + vOff + 4096)  = prV1;
    *(int4*)(smem + L_V + vOff + 8192)  = prV2;
    *(int4*)(smem + L_V + vOff + 12288) = prV3;
    __syncthreads();
    if (NTK > 1) {   // issue tile-1 loads; drain at end of compute(0)
        prK0 = kg[1024+tid]; prK1 = kg[1280+tid]; prK2 = kg[1536+tid]; prK3 = kg[1792+tid];
        prV0 = *(const int4*)(vg + 64);
        prV1 = *(const int4*)(vg + (size_t)32 * NPIX + 64);
        prV2 = *(const int4*)(vg + (size_t)64 * NPIX + 64);
        prV3 = *(const int4*)(vg + (size_t)96 * NPIX + 64);
    }

    f32x4 acc[8];
    const f32x4 fzero = {0.f, 0.f, 0.f, 0.f};
    #pragma unroll
    for (int i = 0; i < 8; ++i) acc[i] = fzero;
    float mrun = -1e30f, lrun = 0.f;
    char* Pw = smem + L_P + w * 1280;

    for (int kt = 0; kt < NTK; ++kt) {
        f32x4 sa0 = fzero, sa1 = fzero;
        {
            const char* rb0 = smem + (kh * 32 + l15) * 256;
            const char* rb1 = rb0 + 4096;
            const int sw = l15 << 4;
            __builtin_amdgcn_s_setprio(1);
            #pragma unroll
            for (int kc = 0; kc < 4; ++kc) {
                int off = (64 * kc + 16 * g) ^ sw;
                bf16x8 a0 = *(const bf16x8*)(rb0 + off);
                bf16x8 a1 = *(const bf16x8*)(rb1 + off);
                sa0 = __builtin_amdgcn_mfma_f32_16x16x32_bf16(a0, qf[kc], sa0, 0, 0, 0);
                sa1 = __builtin_amdgcn_mfma_f32_16x16x32_bf16(a1, qf[kc], sa1, 0, 0, 0);
            }
            __builtin_amdgcn_s_setprio(0);
        }
        {
            int kg0 = (t0 + kt) * 64;
            if (kg0 + 64 > cntK) {
                int kb = cntK - kg0;
                int kr = kh * 32 + 4 * g;
                #pragma unroll
                for (int r = 0; r < 4; ++r) {
                    if (kr + r >= kb)      sa0[r] = -3e38f;
                    if (kr + 16 + r >= kb) sa1[r] = -3e38f;
                }
            }
        }
        float tmax = fmaxf(fmaxf(fmaxf(sa0[0], sa0[1]), fmaxf(sa0[2], sa0[3])),
                           fmaxf(fmaxf(sa1[0], sa1[1]), fmaxf(sa1[2], sa1[3])));
        tmax = fmaxf(tmax, __shfl_xor(tmax, 16));
        tmax = fmaxf(tmax, __shfl_xor(tmax, 32));
        bool grow = !__all(tmax <= mrun + 8.f);
        float mnew = grow ? fmaxf(mrun, tmax) : mrun;
        float p0[4], p1[4];
        float ts = 0.f;
        #pragma unroll
        for (int r = 0; r < 4; ++r) { p0[r] = __expf(sa0[r] - mnew); ts += p0[r]; }
        #pragma unroll
        for (int r = 0; r < 4; ++r) { p1[r] = __expf(sa1[r] - mnew); ts += p1[r]; }
        ts += __shfl_xor(ts, 16);
        ts += __shfl_xor(ts, 32);
        if (grow) {
            float sc = __expf(mrun - mnew);
            lrun = lrun * sc + ts;
            float scr[4];
            #pragma unroll
            for (int r = 0; r < 4; ++r) scr[r] = __shfl(sc, 4 * g + r);
            #pragma unroll
            for (int ct = 0; ct < 8; ++ct) {
                acc[ct][0] *= scr[0]; acc[ct][1] *= scr[1];
                acc[ct][2] *= scr[2]; acc[ct][3] *= scr[3];
            }
            mrun = mnew;
        } else {
            lrun += ts;
        }
        union { __hip_bfloat162 h; unsigned u; } ua0, ua1, ub0, ub1;
        ua0.h.x = __float2bfloat16(p0[0]); ua0.h.y = __float2bfloat16(p0[1]);
        ua1.h.x = __float2bfloat16(p0[2]); ua1.h.y = __float2bfloat16(p0[3]);
        ub0.h.x = __float2bfloat16(p1[0]); ub0.h.y = __float2bfloat16(p1[1]);
        ub1.h.x = __float2bfloat16(p1[2]); ub1.h.y = __float2bfloat16(p1[3]);
        *(int2*)(Pw + l15 * 80 +      8 * g) = make_int2((int)ua0.u, (int)ua1.u);
        *(int2*)(Pw + l15 * 80 + 32 + 8 * g) = make_int2((int)ub0.u, (int)ub1.u);
        bf16x8 pf = *(const bf16x8*)(Pw + l15 * 80 + 16 * g);
        {
            const char* bv = smem + L_V;
            __builtin_amdgcn_s_setprio(1);
            #pragma unroll
            for (int ct = 0; ct < 8; ++ct) {
                int c = 16 * ct + l15;
                bf16x8 vf = *(const bf16x8*)(bv + c * 128 +
                                             ((64 * kh + 16 * g) ^ ((c & 7) << 4)));
                acc[ct] = __builtin_amdgcn_mfma_f32_16x16x32_bf16(pf, vf, acc[ct], 0, 0, 0);
            }
            __builtin_amdgcn_s_setprio(0);
        }
        __syncthreads();   // barrier1: compute done; tile-(kt+1) loads drained here
        if (kt + 1 < NTK) {
            *(int4*)(smem + kOff)          = prK0;
            *(int4*)(smem + kOff + 4096)   = prK1;
            *(int4*)(smem + kOff + 8192)   = prK2;
            *(int4*)(smem + kOff + 12288)  = prK3;
            *(int4*)(smem + L_V + vOff)         = prV0;
            *(int4*)(smem + L_V + vOff + 4096)  = prV1;
            *(int4*)(smem + L_V + vOff + 8192)  = prV2;
            *(int4*)(smem + L_V + vOff + 12288) = prV3;
            __syncthreads();   // barrier2: vmcnt already 0, cheap
            if (kt + 2 < NTK) {
                int tb = (kt + 2) * 1024;
                prK0 = kg[tb+tid]; prK1 = kg[tb+256+tid];
                prK2 = kg[tb+512+tid]; prK3 = kg[tb+768+tid];
                const ushort* vgk = vg + (kt + 2) * 64;
                prV0 = *(const int4*)(vgk);
                prV1 = *(const int4*)(vgk + (size_t)32 * NPIX);
                prV2 = *(const int4*)(vgk + (size_t)64 * NPIX);
                prV3 = *(const int4*)(vgk + (size_t)96 * NPIX);
            }
        }
    }

    // ---- merge 2 key-halves; write unnormalized partial + (m,l) ----
    float* ma = (float*)(smem + L_ML);   // [2][32]
    float* la = ma + 64;
    const int qs = wq * 16 + l15;
    if (g == 0) { ma[kh * 32 + qs] = mrun; la[kh * 32 + qs] = lrun; }
    __syncthreads();
    float* agg = (float*)smem;           // [128][36] fp32, reuses K/V region
    {
        float mstar = fmaxf(ma[qs], ma[32 + qs]);
        float f = __expf(mrun - mstar);
        float fr[4];
        #pragma unroll
        for (int r = 0; r < 4; ++r) fr[r] = __shfl(f, 4 * g + r);
        if (kh == 1) {
            #pragma unroll
            for (int ct = 0; ct < 8; ++ct) {
                int c = 16 * ct + l15;
                #pragma unroll
                for (int r = 0; r < 4; ++r)
                    agg[c * 36 + wq * 16 + 4 * g + r] = acc[ct][r] * fr[r];
            }
        }
        __syncthreads();
        if (kh == 0) {
            #pragma unroll
            for (int ct = 0; ct < 8; ++ct) {
                int c = 16 * ct + l15;
                #pragma unroll
                for (int r = 0; r < 4; ++r) {
                    int idx = c * 36 + wq * 16 + 4 * g + r;
                    agg[idx] = acc[ct][r] * fr[r] + agg[idx];
                }
            }
        }
    }
    __syncthreads();
    if (tid < 32) {
        float M = fmaxf(ma[tid], ma[32 + tid]);
        float ls = la[tid] * __expf(ma[tid] - M) + la[32 + tid] * __expf(ma[32 + tid] - M);
        *(float2*)(mlW + ((size_t)blk * 32 + tid) * 2) = make_float2(M, ls);
    }
    ushort* pdst = partW + (size_t)blk * 4096;
    #pragma unroll
    for (int it = 0; it < 8; ++it) {
        int idx = it * 256 + tid;
        int c = idx >> 4, n2 = (idx & 15) * 2;
        __hip_bfloat162 h;
        h.x = __float2bfloat16(agg[c * 36 + n2]);
        h.y = __float2bfloat16(agg[c * 36 + n2 + 1]);
        *(__hip_bfloat162*)(pdst + c * 32 + n2) = h;
    }
}

// ---------------- comb: slot-space combine + scatter (128 qblks) ----
__global__ __launch_bounds__(256) void sffa_comb(
    const ushort* __restrict__ partW, const float* __restrict__ mlW,
    const float* __restrict__ s0c, const int* __restrict__ pixQ,
    const int* __restrict__ cnts, float* __restrict__ out, int KS)
{
    __shared__ float wgtL[4][32];
    __shared__ int pixnL[32];
    const int tid = threadIdx.x;
    const int bx = blockIdx.x;
    const int b = bx >> 7, qb = bx & 127;
    const int cntK = cnts[b * 2], cntQ = cnts[b * 2 + 1];
    if (qb * 32 >= cntQ) return;
    const int blkbase = (b * 128 + qb) * KS;
    const float m0f = (float)(NPIX - cntK);

    if (tid < 32) {
        int slot = qb * 32 + tid;
        int pix = -1;
        if (slot < cntQ) {
            pix = pixQ[(size_t)b * NPIX + slot];
            float s0 = s0c[(size_t)b * NPIX + slot];
            float M = s0;
            float2 mls[4];
            #pragma unroll
            for (int k = 0; k < 4; ++k) {
                if (k < KS) {
                    mls[k] = *(const float2*)(mlW + ((size_t)(blkbase + k) * 32 + tid) * 2);
                    M = fmaxf(M, mls[k].x);
                }
            }
            float L = m0f * __expf(s0 - M);
            #pragma unroll
            for (int k = 0; k < 4; ++k)
                if (k < KS) L += mls[k].y * __expf(mls[k].x - M);
            float Li = 1.f / L;
            #pragma unroll
            for (int k = 0; k < 4; ++k)
                if (k < KS) wgtL[k][tid] = __expf(mls[k].x - M) * Li;
        }
        pixnL[tid] = pix;
    }
    __syncthreads();

    float* ob = out + (size_t)b * NC * NPIX;
    const ushort* pb = partW + (size_t)blkbase * 4096;
    {
        int c = tid >> 1, grp = tid & 1;     // c 0..127, 16-slot group
        float v[16];
        #pragma unroll
        for (int j = 0; j < 16; ++j) v[j] = 0.f;
        #pragma unroll
        for (int k = 0; k < 4; ++k) {
            if (k < KS) {
                ushort u[16];
                *(int4*)(u)     = *(const int4*)(pb + (size_t)k * 4096 + c * 32 + grp * 16);
                *(int4*)(u + 8) = *(const int4*)(pb + (size_t)k * 4096 + c * 32 + grp * 16 + 8);
                #pragma unroll
                for (int j = 0; j < 16; ++j)
                    v[j] = fmaf(__uint_as_float((unsigned)u[j] << 16),
                                wgtL[k][grp * 16 + j], v[j]);
            }
        }
        #pragma unroll
        for (int j = 0; j < 16; ++j) {
            int pix = pixnL[grp * 16 + j];
            if (pix >= 0) ob[(size_t)c * NPIX + pix] = v[j];
        }
    }
}

extern "C" void kernel_launch(void* const* d_in, const int* in_sizes, int n_in,
                              void* d_out, int out_size, void* d_ws, size_t ws_size,
                              hipStream_t stream) {
    const float* x    = (const float*)d_in[0];
    const float* mask = (const float*)d_in[1];
    char* ws = (char*)d_ws;
    const size_t MBy = 1024 * 1024;
    const size_t KBy = 1024;

    ushort* KnW = (ushort*)(ws);                      // 4 MB compact Kn
    ushort* QW  = (ushort*)(ws + 4 * MBy);            // 4 MB compact Q
    ushort* VtW = (ushort*)(ws + 8 * MBy);            // 4 MB compact V^T

    size_t need4 = 12 * MBy + 16 * MBy + 1 * MBy;
    int KS = (ws_size >= need4) ? 4 : 2;
    ushort* partW = (ushort*)(ws + 12 * MBy);         // 4*128*KS blocks * 8 KB = KS*4 MB
    char* tail = ws + 12 * MBy + (size_t)KS * 4 * MBy;
    float* mlW  = (float*)(tail);                      // 4*128*KS * 256 B <= 512 KB
    float* s0c  = (float*)(tail + 576 * KBy);          // 64 KB
    int*   pixQ = (int*)(tail + 640 * KBy);            // 64 KB
    int*   cnts = (int*)(tail + 704 * KBy);            // 32 B

    sffa_prep <<<256, 1024, 0, stream>>>(x, mask, KnW, QW, VtW, s0c, pixQ, cnts,
                                         (float*)d_out);
    sffa_attn <<<4 * 128 * KS, 256, 0, stream>>>(KnW, QW, VtW, cnts, partW, mlW, KS);
    sffa_comb <<<4 * 128, 256, 0, stream>>>(partW, mlW, s0c, pixQ, cnts,
                                            (float*)d_out, KS);
}

// Round 14
// 54.560 us; speedup vs baseline: 1.2210x; 1.1406x over previous
//
#include <hip/hip_runtime.h>
#include <hip/hip_bf16.h>

typedef __attribute__((ext_vector_type(8))) short bf16x8;
typedef __attribute__((ext_vector_type(4))) float f32x4;

#define NPIX 4096
#define NC   128
#define RS128 0.08838834764831845f   // 1/sqrt(128)

// global -> LDS direct DMA, 16B per lane (linear dest = wave-uniform base + lane*16)
#define GL2LDS(g, l) __builtin_amdgcn_global_load_lds( \
    (const __attribute__((address_space(1))) void*)(g), \
    (__attribute__((address_space(3))) void*)(l), 16, 0, 0)

// ---------------- prep (fused scan + copy + pack), 1024 thr — r8 verbatim ----------------
__global__ __launch_bounds__(1024) void sffa_prep(
    const float* __restrict__ x, const float* __restrict__ mask,
    ushort* __restrict__ KnW, ushort* __restrict__ QW, ushort* __restrict__ VtW,
    float* __restrict__ s0c, int* __restrict__ pixQ, int* __restrict__ cnts,
    float* __restrict__ out)
{
    __shared__ float xs[128][69];
    __shared__ float ms[64];
    __shared__ float rinv[64];
    __shared__ float ssum[64];
    __shared__ float2 part[16][64];
    __shared__ int se[64];
    __shared__ int bgn[64];
    __shared__ int tinfo[2];
    __shared__ int wredP[16], wredT[16];
    const int tid = threadIdx.x;
    const int b = blockIdx.x >> 6, nblk = blockIdx.x & 63;
    const int n0 = nblk * 64;
    const float* xb = x + (size_t)b * NC * NPIX;
    float* ob = out + (size_t)b * NC * NPIX;

    #pragma unroll
    for (int it = 0; it < 2; ++it) {
        int e4 = it * 1024 + tid;
        int c = e4 >> 4, n4 = (e4 & 15) * 4;
        float4 v = *(const float4*)(xb + (size_t)c * NPIX + n0 + n4);
        xs[c][n4+0] = v.x; xs[c][n4+1] = v.y; xs[c][n4+2] = v.z; xs[c][n4+3] = v.w;
        *(float4*)(ob + (size_t)c * NPIX + n0 + n4) = v;
    }
    if (tid < 16) {
        float4 mv = *(const float4*)(mask + (size_t)b * NPIX + n0 + tid * 4);
        ms[tid*4+0] = mv.x; ms[tid*4+1] = mv.y; ms[tid*4+2] = mv.z; ms[tid*4+3] = mv.w;
    }
    {
        const int lane = tid & 63, w = tid >> 6;
        float4 mv = *(const float4*)(mask + (size_t)b * NPIX + tid * 4);
        int f0 = mv.x < 0.5f ? 0x10000 : 1;
        int f1 = mv.y < 0.5f ? 0x10000 : 1;
        int f2 = mv.z < 0.5f ? 0x10000 : 1;
        int f3 = mv.w < 0.5f ? 0x10000 : 1;
        int p0 = tid * 4;
        int pre = 0, tot = f0 + f1 + f2 + f3;
        if (p0 + 0 < n0) pre += f0;
        if (p0 + 1 < n0) pre += f1;
        if (p0 + 2 < n0) pre += f2;
        if (p0 + 3 < n0) pre += f3;
        #pragma unroll
        for (int d = 1; d < 64; d <<= 1) {
            pre += __shfl_xor(pre, d);
            tot += __shfl_xor(tot, d);
        }
        if (lane == 0) { wredP[w] = pre; wredT[w] = tot; }
    }
    __syncthreads();
    if (tid < 64) {
        int vP = (tid < 16) ? wredP[tid] : 0;
        int vT = (tid < 16) ? wredT[tid] : 0;
        #pragma unroll
        for (int d = 1; d < 16; d <<= 1) {
            vP += __shfl_xor(vP, d);
            vT += __shfl_xor(vT, d);
        }
        int base  = __shfl(vP, 0);
        int total = __shfl(vT, 0);
        if (tid == 0 && nblk == 0) {
            cnts[b * 2]     = total & 0xffff;
            cnts[b * 2 + 1] = total >> 16;
        }
        int f = ms[tid] > 0.5f ? 1 : 0x10000;
        int s = f;
        #pragma unroll
        for (int d = 1; d < 64; d <<= 1) {
            int t = __shfl_up(s, d);
            if (tid >= d) s += t;
        }
        se[tid] = base + s - f;
    }
    __syncthreads();
    {
        int p = tid & 63, qd = tid >> 6;
        float m = ms[p];
        float s2 = 0.f, s1 = 0.f;
        #pragma unroll
        for (int i = 0; i < 8; ++i) {
            float xv = xs[qd*8 + i][p];
            float k = fmaf(xv, m, 1e-7f);
            s2 = fmaf(k, k, s2);
            s1 += xv;
        }
        part[qd][p] = make_float2(s2, s1);
    }
    __syncthreads();
    if (tid < 64) {
        float s2 = 0.f, s1 = 0.f;
        #pragma unroll
        for (int k = 0; k < 16; ++k) { float2 t = part[k][tid]; s2 += t.x; s1 += t.y; }
        rinv[tid] = rsqrtf(s2);
        ssum[tid] = s1 * RS128;
    }
    __syncthreads();
    #pragma unroll
    for (int it = 0; it < 4; ++it) {
        int e2 = it * 1024 + tid;
        int n = e2 >> 6, cp = (e2 & 63) * 2;
        int pe = se[n];
        float x0 = xs[cp][n], x1 = xs[cp+1][n];
        if (ms[n] > 0.5f) {
            int slot = pe & 0xffff;
            float k0 = x0 + 1e-7f, k1 = x1 + 1e-7f;
            float r = rinv[n];
            __hip_bfloat162 kn;
            kn.x = __float2bfloat16(k0 * r); kn.y = __float2bfloat16(k1 * r);
            *(__hip_bfloat162*)(KnW + ((size_t)b * NPIX + slot) * NC + cp) = kn;
        } else {
            int slot = pe >> 16;
            __hip_bfloat162 q;
            q.x = __float2bfloat16(x0); q.y = __float2bfloat16(x1);
            *(__hip_bfloat162*)(QW + ((size_t)b * NPIX + slot) * NC + cp) = q;
        }
    }
    if (tid < 64) {
        if (ms[tid] < 0.5f) {
            int slot = se[tid] >> 16;
            s0c [(size_t)b * NPIX + slot] = ssum[tid];
            pixQ[(size_t)b * NPIX + slot] = n0 + tid;
        } else {
            bgn[(se[tid] & 0xffff) - (se[0] & 0xffff)] = tid;
        }
    }
    if (tid == 0) {
        tinfo[0] = se[0] & 0xffff;
        tinfo[1] = (se[63] & 0xffff) + (ms[63] > 0.5f ? 1 : 0) - (se[0] & 0xffff);
    }
    __syncthreads();
    {
        const int s0b = tinfo[0], nbg = tinfo[1];
        const int j = tid & 63, cg = tid >> 6;
        if (j < nbg) {
            int n = bgn[j];
            ushort* vcol = VtW + (size_t)b * NC * NPIX + s0b + j;
            #pragma unroll
            for (int cc = 0; cc < 8; ++cc) {
                int c = cg * 8 + cc;
                __hip_bfloat16 h = __float2bfloat16(xs[c][n] + 1e-7f);
                vcol[(size_t)c * NPIX] = *(ushort*)&h;
            }
        }
    }
}

// ---------------- attn: r8 geometry (512 thr, 64q, 64k, KS) + global_load_lds staging ----
#define L_BUF 32768
#define L_P   65536
#define L_ML  75776
#define L_SZ  76800

__global__ __launch_bounds__(512, 4) void sffa_attn(
    const ushort* __restrict__ KnW, const ushort* __restrict__ QW,
    const ushort* __restrict__ VtW, const int* __restrict__ cnts,
    ushort* __restrict__ partW, float* __restrict__ mlW, int KS)
{
    __shared__ __align__(16) char smem[L_SZ];
    const int tid  = threadIdx.x;
    const int w = tid >> 6, lane = tid & 63;
    const int l15 = lane & 15, g = lane >> 4;
    const int bx = (int)blockIdx.x;
    const int per = 64 * KS;
    const int b = bx / per;
    const int rem = bx - b * per;
    const int qblk = rem / KS, ks = rem - (rem / KS) * KS;
    const int q0 = qblk * 64;
    const int cntK = cnts[b * 2], cntQ = cnts[b * 2 + 1];
    if (q0 >= cntQ) return;
    const int blk = (b * 64 + qblk) * KS + ks;

    const int nk64 = (cntK + 63) >> 6;
    const int tpk  = (nk64 + KS - 1) / KS;
    const int t0   = ks * tpk;
    const int NTK  = min(t0 + tpk, nk64) - t0;

    if (NTK <= 0) {
        unsigned* pz = (unsigned*)(partW + (size_t)blk * 8192);
        #pragma unroll
        for (int i = 0; i < 8; ++i) pz[i * 512 + tid] = 0u;
        if (tid < 64)
            *(float2*)(mlW + ((size_t)blk * 64 + tid) * 2) = make_float2(-1e30f, 0.f);
        return;
    }

    const int half = w >> 2;
    const int wq   = w & 3;
    const int kbase = t0 * 64;

    const ushort* Knb = KnW + (size_t)b * NPIX * NC;
    const ushort* Vtb = VtW + (size_t)b * NC * NPIX;

    // Q fragments direct from global (L2-hot, once per block)
    bf16x8 qf[4];
    {
        const ushort* Qrow = QW + ((size_t)b * NPIX + q0 + wq * 16 + l15) * NC;
        #pragma unroll
        for (int kc = 0; kc < 4; ++kc)
            qf[kc] = *(const bf16x8*)(Qrow + 32 * kc + 8 * g);
    }

    // pre-swizzled GLOBAL sources (G21: inverse-swz source + linear LDS dest)
    const int rK = tid >> 4;                      // K row 0..31 (issue2: +32)
    const char* srcK = (const char*)(Knb + (size_t)(kbase + rK) * NC)
                     + (((tid & 15) ^ (rK & 15)) << 4);
    const int rV = tid >> 3;                      // V c-row 0..63 (issue2: +64)
    const char* srcV = (const char*)(Vtb + (size_t)rV * NPIX + kbase)
                     + (((tid & 7) ^ (rV & 7)) << 4);
    char* d0 = smem + tid * 16;                   // linear dests

    // stage tile 0 into buf0
    GL2LDS(srcK,        d0);
    GL2LDS(srcK + 8192, d0 + 8192);
    GL2LDS(srcV,                           d0 + 16384);
    GL2LDS(srcV + (size_t)64 * NPIX * 2,   d0 + 24576);
    __syncthreads();     // drains DMA; buf0 ready

    f32x4 acc[8];
    const f32x4 fzero = {0.f, 0.f, 0.f, 0.f};
    #pragma unroll
    for (int i = 0; i < 8; ++i) acc[i] = fzero;
    float mrun = -1e30f, lrun = 0.f;
    char* Pw = smem + L_P + w * 1280;

    for (int kt = 0; kt < NTK; ++kt) {
        if (kt + 1 < NTK) {
            // issue next-tile DMAs; they fly during compute, drained by end barrier
            char* nb = smem + ((kt + 1) & 1) * L_BUF + tid * 16;
            const char* sK = srcK + (size_t)(kt + 1) * 16384;   // 64 rows * 256 B
            const char* sV = srcV + (size_t)(kt + 1) * 128;     // 64 keys * 2 B
            GL2LDS(sK,        nb);
            GL2LDS(sK + 8192, nb + 8192);
            GL2LDS(sV,                         nb + 16384);
            GL2LDS(sV + (size_t)64 * NPIX * 2, nb + 24576);
        }
        char* bb = smem + (kt & 1) * L_BUF;
        f32x4 sa0 = fzero, sa1 = fzero;
        {
            const char* rb0 = bb + (half * 32 + l15) * 256;
            const char* rb1 = rb0 + 4096;
            const int sw = l15 << 4;
            __builtin_amdgcn_s_setprio(1);
            #pragma unroll
            for (int kc = 0; kc < 4; ++kc) {
                int off = (64 * kc + 16 * g) ^ sw;
                bf16x8 a0 = *(const bf16x8*)(rb0 + off);
                bf16x8 a1 = *(const bf16x8*)(rb1 + off);
                sa0 = __builtin_amdgcn_mfma_f32_16x16x32_bf16(a0, qf[kc], sa0, 0, 0, 0);
                sa1 = __builtin_amdgcn_mfma_f32_16x16x32_bf16(a1, qf[kc], sa1, 0, 0, 0);
            }
            __builtin_amdgcn_s_setprio(0);
        }
        {
            int kg0 = (t0 + kt) * 64;
            if (kg0 + 64 > cntK) {
                int kb = cntK - kg0;
                int kr = half * 32 + 4 * g;
                #pragma unroll
                for (int r = 0; r < 4; ++r) {
                    if (kr + r >= kb)      sa0[r] = -3e38f;
                    if (kr + 16 + r >= kb) sa1[r] = -3e38f;
                }
            }
        }
        float tmax = fmaxf(fmaxf(fmaxf(sa0[0], sa0[1]), fmaxf(sa0[2], sa0[3])),
                           fmaxf(fmaxf(sa1[0], sa1[1]), fmaxf(sa1[2], sa1[3])));
        tmax = fmaxf(tmax, __shfl_xor(tmax, 16));
        tmax = fmaxf(tmax, __shfl_xor(tmax, 32));
        bool grow = !__all(tmax <= mrun + 8.f);
        float mnew = grow ? fmaxf(mrun, tmax) : mrun;
        float p0[4], p1[4];
        float ts = 0.f;
        #pragma unroll
        for (int r = 0; r < 4; ++r) { p0[r] = __expf(sa0[r] - mnew); ts += p0[r]; }
        #pragma unroll
        for (int r = 0; r < 4; ++r) { p1[r] = __expf(sa1[r] - mnew); ts += p1[r]; }
        ts += __shfl_xor(ts, 16);
        ts += __shfl_xor(ts, 32);
        if (grow) {
            float sc = __expf(mrun - mnew);
            lrun = lrun * sc + ts;
            float scr[4];
            #pragma unroll
            for (int r = 0; r < 4; ++r) scr[r] = __shfl(sc, 4 * g + r);
            #pragma unroll
            for (int ct = 0; ct < 8; ++ct) {
                acc[ct][0] *= scr[0]; acc[ct][1] *= scr[1];
                acc[ct][2] *= scr[2]; acc[ct][3] *= scr[3];
            }
            mrun = mnew;
        } else {
            lrun += ts;
        }
        union { __hip_bfloat162 h; unsigned u; } ua0, ua1, ub0, ub1;
        ua0.h.x = __float2bfloat16(p0[0]); ua0.h.y = __float2bfloat16(p0[1]);
        ua1.h.x = __float2bfloat16(p0[2]); ua1.h.y = __float2bfloat16(p0[3]);
        ub0.h.x = __float2bfloat16(p1[0]); ub0.h.y = __float2bfloat16(p1[1]);
        ub1.h.x = __float2bfloat16(p1[2]); ub1.h.y = __float2bfloat16(p1[3]);
        *(int2*)(Pw + l15 * 80 +      8 * g) = make_int2((int)ua0.u, (int)ua1.u);
        *(int2*)(Pw + l15 * 80 + 32 + 8 * g) = make_int2((int)ub0.u, (int)ub1.u);
        bf16x8 pf = *(const bf16x8*)(Pw + l15 * 80 + 16 * g);
        {
            const char* vb = bb + 16384;
            __builtin_amdgcn_s_setprio(1);
            #pragma unroll
            for (int ct = 0; ct < 8; ++ct) {
                int c = 16 * ct + l15;
                bf16x8 vf = *(const bf16x8*)(vb + c * 128 +
                                             ((64 * half + 16 * g) ^ ((c & 7) << 4)));
                acc[ct] = __builtin_amdgcn_mfma_f32_16x16x32_bf16(pf, vf, acc[ct], 0, 0, 0);
            }
            __builtin_amdgcn_s_setprio(0);
        }
        __syncthreads();   // drains next-tile DMA + syncs waves
    }

    // ---- merge key-half partials; write unnormalized partial + (m,l) — r8 verbatim ----
    float* ma = (float*)(smem + L_ML);
    float* la = ma + 64; float* mb = la + 64; float* lb = mb + 64;
    const int q = wq * 16 + l15;
    if (g == 0) {
        if (half == 0) { ma[q] = mrun; la[q] = lrun; }
        else           { mb[q] = mrun; lb[q] = lrun; }
    }
    __syncthreads();
    float* agg = (float*)smem;
    {
        float mstar = fmaxf(ma[q], mb[q]);
        float f = __expf(mrun - mstar);
        float fr[4];
        #pragma unroll
        for (int r = 0; r < 4; ++r) fr[r] = __shfl(f, 4 * g + r);
        if (half == 1) {
            #pragma unroll
            for (int ct = 0; ct < 8; ++ct) {
                int c = 16 * ct + l15;
                #pragma unroll
                for (int r = 0; r < 4; ++r)
                    agg[c * 68 + wq * 16 + 4 * g + r] = acc[ct][r] * fr[r];
            }
        }
        __syncthreads();
        if (half == 0) {
            #pragma unroll
            for (int ct = 0; ct < 8; ++ct) {
                int c = 16 * ct + l15;
                #pragma unroll
                for (int r = 0; r < 4; ++r) {
                    int idx = c * 68 + wq * 16 + 4 * g + r;
                    agg[idx] = acc[ct][r] * fr[r] + agg[idx];
                }
            }
        }
    }
    __syncthreads();
    if (tid < 64) {
        float M = fmaxf(ma[tid], mb[tid]);
        float ls = la[tid] * __expf(ma[tid] - M) + lb[tid] * __expf(mb[tid] - M);
        *(float2*)(mlW + ((size_t)blk * 64 + tid) * 2) = make_float2(M, ls);
    }
    ushort* pdst = partW + (size_t)blk * 8192;
    #pragma unroll
    for (int it = 0; it < 8; ++it) {
        int idx = it * 512 + tid;
        int c = idx >> 5, n2 = (idx & 31) * 2;
        __hip_bfloat162 h;
        h.x = __float2bfloat16(agg[c * 68 + n2]);
        h.y = __float2bfloat16(agg[c * 68 + n2 + 1]);
        *(__hip_bfloat162*)(pdst + c * 64 + n2) = h;
    }
}

// ---------------- comb: slot-space combine + scatter — r8 verbatim ----------------
__global__ __launch_bounds__(256) void sffa_comb(
    const ushort* __restrict__ partW, const float* __restrict__ mlW,
    const float* __restrict__ s0c, const int* __restrict__ pixQ,
    const int* __restrict__ cnts, float* __restrict__ out, int KS)
{
    __shared__ float wgtL[4][64];
    __shared__ int pixnL[64];
    const int tid = threadIdx.x;
    const int bx = blockIdx.x;
    const int b = bx >> 7, qb = (bx >> 1) & 63, ch = bx & 1;
    const int cntK = cnts[b * 2], cntQ = cnts[b * 2 + 1];
    if (qb * 64 >= cntQ) return;
    const int blkbase = (b * 64 + qb) * KS;
    const float m0f = (float)(NPIX - cntK);

    if (tid < 64) {
        int slot = qb * 64 + tid;
        int pix = -1;
        if (slot < cntQ) {
            pix = pixQ[(size_t)b * NPIX + slot];
            float s0 = s0c[(size_t)b * NPIX + slot];
            float M = s0;
            float2 mls[4];
            #pragma unroll
            for (int k = 0; k < 4; ++k) {
                if (k < KS) {
                    mls[k] = *(const float2*)(mlW + ((size_t)(blkbase + k) * 64 + tid) * 2);
                    M = fmaxf(M, mls[k].x);
                }
            }
            float L = m0f * __expf(s0 - M);
            #pragma unroll
            for (int k = 0; k < 4; ++k)
                if (k < KS) L += mls[k].y * __expf(mls[k].x - M);
            float Li = 1.f / L;
            #pragma unroll
            for (int k = 0; k < 4; ++k)
                if (k < KS) wgtL[k][tid] = __expf(mls[k].x - M) * Li;
        }
        pixnL[tid] = pix;
    }
    __syncthreads();

    float* ob = out + ((size_t)b * NC + ch * 64) * NPIX;
    const ushort* pb = partW + (size_t)blkbase * 8192 + ch * 4096;
    #pragma unroll
    for (int it = 0; it < 2; ++it) {
        int idx = it * 256 + tid;
        int c = idx >> 3, grp = idx & 7;
        float v[8] = {0.f,0.f,0.f,0.f,0.f,0.f,0.f,0.f};
        #pragma unroll
        for (int k = 0; k < 4; ++k) {
            if (k < KS) {
                ushort u[8];
                *(int4*)u = *(const int4*)(pb + (size_t)k * 8192 + c * 64 + grp * 8);
                #pragma unroll
                for (int j = 0; j < 8; ++j)
                    v[j] = fmaf(__uint_as_float((unsigned)u[j] << 16),
                                wgtL[k][grp * 8 + j], v[j]);
            }
        }
        #pragma unroll
        for (int j = 0; j < 8; ++j) {
            int pix = pixnL[grp * 8 + j];
            if (pix >= 0) ob[(size_t)c * NPIX + pix] = v[j];
        }
    }
}

extern "C" void kernel_launch(void* const* d_in, const int* in_sizes, int n_in,
                              void* d_out, int out_size, void* d_ws, size_t ws_size,
                              hipStream_t stream) {
    const float* x    = (const float*)d_in[0];
    const float* mask = (const float*)d_in[1];
    char* ws = (char*)d_ws;
    const size_t MBy = 1024 * 1024;
    const size_t KBy = 1024;

    ushort* KnW = (ushort*)(ws);                      // 4 MB compact Kn
    ushort* QW  = (ushort*)(ws + 4 * MBy);            // 4 MB compact Q
    ushort* VtW = (ushort*)(ws + 8 * MBy);            // 4 MB compact V^T

    size_t need4 = 12 * MBy + 16 * MBy + 1 * MBy;
    int KS = (ws_size >= need4) ? 4 : 2;
    ushort* partW = (ushort*)(ws + 12 * MBy);                       // KS*4 MB
    char* tail = ws + 12 * MBy + (size_t)KS * 4 * MBy;
    float* mlW  = (float*)(tail);                                    // 512 KB
    float* s0c  = (float*)(tail + 576 * KBy);                        // 64 KB
    int*   pixQ = (int*)(tail + 640 * KBy);                          // 64 KB
    int*   cnts = (int*)(tail + 704 * KBy);                          // 32 B

    sffa_prep <<<256, 1024, 0, stream>>>(x, mask, KnW, QW, VtW, s0c, pixQ, cnts,
                                         (float*)d_out);
    sffa_attn <<<4 * 64 * KS, 512, 0, stream>>>(KnW, QW, VtW, cnts, partW, mlW, KS);
    sffa_comb <<<4 * 128, 256, 0, stream>>>(partW, mlW, s0c, pixQ, cnts,
                                            (float*)d_out, KS);
}